// Round 3
// baseline (542.121 us; speedup 1.0000x reference)
//
#include <hip/hip_runtime.h>
#include <hip/hip_bf16.h>

#define BB 4
#define CC 64
#define HH 128
#define WW 128
#define HW (HH * WW)

typedef short bf16x8 __attribute__((ext_vector_type(8)));
typedef float f32x4 __attribute__((ext_vector_type(4)));

static __device__ __forceinline__ short f2bf(float f) {
  __hip_bfloat16 h = __float2bfloat16(f);
  return __builtin_bit_cast(short, h);
}
static __device__ __forceinline__ float bf2f(short s) {
  unsigned int u = ((unsigned int)(unsigned short)s) << 16;
  return __builtin_bit_cast(float, u);
}

// Cast two f32 tensors (same length n, n%4==0) to bf16.
__global__ __launch_bounds__(256) void cast_bf16_kernel(
    const float* __restrict__ a, const float* __restrict__ b,
    short* __restrict__ oa, short* __restrict__ ob, int n) {
  for (int i = blockIdx.x * 256 + threadIdx.x; i < n / 4;
       i += gridDim.x * 256) {
    float4 va = ((const float4*)a)[i];
    short4 s;
    s.x = f2bf(va.x); s.y = f2bf(va.y); s.z = f2bf(va.z); s.w = f2bf(va.w);
    ((short4*)oa)[i] = s;
    float4 vb = ((const float4*)b)[i];
    short4 t;
    t.x = f2bf(vb.x); t.y = f2bf(vb.y); t.z = f2bf(vb.z); t.w = f2bf(vb.w);
    ((short4*)ob)[i] = t;
  }
}

// deform weights (64,64,3,3) -> bf16 A-fragment order [k][cf][ot][lane64][8]
//   lane l, elem j of frag (k,cf,ot): A[o = ot*16 + (l&15)][kdim = (l>>4)*8+j]
//   where kdim = c - cf*32  (mfma_f32_16x16x32_bf16 A layout)
// offset weights (18,128,3,3) -> f32 [k][c][20] (18 o + pad)
__global__ __launch_bounds__(256) void prep_weights(
    const float* __restrict__ wd, const float* __restrict__ wo,
    short* __restrict__ wtd, float* __restrict__ to) {
  int i = blockIdx.x * 256 + threadIdx.x;
  if (i < 9 * 2 * 4 * 64 * 8) {
    int j = i & 7, l = (i >> 3) & 63, ot = (i >> 9) & 3;
    int cf = (i >> 11) & 1, k = i >> 12;
    int o = ot * 16 + (l & 15);
    int c = cf * 32 + (l >> 4) * 8 + j;
    wtd[i] = f2bf(wd[(o * 64 + c) * 9 + k]);
  }
  if (i < 18 * 128 * 9) {
    int o = i / 1152, c = (i / 9) & 127, k = i % 9;
    to[(k * 128 + c) * 20 + o] = wo[i];
  }
}

// Offset conv on bf16 activations: conv3x3(concat(a,x2), w) + bias -> (B,18,H,W) f32
__global__ __launch_bounds__(512, 4) void off_conv_kernel(
    const short* __restrict__ a, const short* __restrict__ x2,
    const float* __restrict__ to, const float* __restrict__ bias,
    float* __restrict__ out) {
  __shared__ float red[3][128][19];
  int bid = blockIdx.x;
  bid = (bid & 7) * (gridDim.x >> 3) + (bid >> 3);
  const int tid = threadIdx.x;
  const int lp = tid & 127;
  const int cq = __builtin_amdgcn_readfirstlane(tid >> 7);
  const int cbase = cq * 32;
  const int pix = bid * 128 + lp;
  const int b = pix >> 14;
  const int hw = pix & (HW - 1);
  const int h = hw >> 7, w = hw & (WW - 1);

  const short* pin = ((cq < 2) ? a : x2) + (size_t)b * (CC * HW)
                     + (size_t)(cq & 1) * 32 * HW;

  float acc[18];
#pragma unroll
  for (int o = 0; o < 18; o++) acc[o] = 0.f;

  for (int k = 0; k < 9; k++) {
    const int ky = k / 3, kx = k - ky * 3;
    const int hh = h + ky - 1, ww2 = w + kx - 1;
    const bool valid = (hh >= 0) & (hh < HH) & (ww2 >= 0) & (ww2 < WW);
    const int idx = hh * WW + ww2;
#pragma unroll 4
    for (int c = 0; c < 32; c++) {
      float v = valid ? bf2f(pin[c * HW + idx]) : 0.f;
      const float* wr = to + (k * 128 + cbase + c) * 20;  // uniform -> s_load
#pragma unroll
      for (int o = 0; o < 18; o++) acc[o] = fmaf(v, wr[o], acc[o]);
    }
  }

  if (cq > 0) {
#pragma unroll
    for (int o = 0; o < 18; o++) red[cq - 1][lp][o] = acc[o];
  }
  __syncthreads();
  if (cq == 0) {
    float* po = out + (size_t)b * (18 * HW) + hw;
#pragma unroll
    for (int o = 0; o < 18; o++)
      po[o * HW] = acc[o] + red[0][lp][o] + red[1][lp][o] + red[2][lp][o]
                   + bias[o];
  }
}

// MFMA deformable conv. Block 256 = 4 waves; wave = 16 px, all 64 outputs.
// Lane l: px = px0 + (l&15), samples c = cf*32 + (l>>4)*8 + j  -> the sampled
// registers ARE the mfma B-fragment. No LDS, no barriers.
__global__ __launch_bounds__(256, 4) void deform_mfma_kernel(
    const short* __restrict__ x, const float* __restrict__ off,
    const short* __restrict__ wtd, const float* __restrict__ bias,
    float* __restrict__ outf, short* __restrict__ outb) {
  int bid = blockIdx.x;
  bid = (bid & 7) * (gridDim.x >> 3) + (bid >> 3);
  const int tid = threadIdx.x;
  const int l = tid & 63;
  const int wv = tid >> 6;
  const int col = l & 15;
  const int quad = l >> 4;
  const int px0 = bid * 64 + wv * 16;
  const int pix = px0 + col;
  const int b = pix >> 14;
  const int hw = pix & (HW - 1);
  const int h = hw >> 7, w = hw & (WW - 1);

  const short* xq = x + (size_t)b * (CC * HW) + (size_t)quad * 8 * HW;
  const float* offb = off + (size_t)b * (18 * HW) + hw;

  f32x4 acc[4];
#pragma unroll
  for (int ot = 0; ot < 4; ot++)
#pragma unroll
    for (int r = 0; r < 4; r++) acc[ot][r] = bias[ot * 16 + quad * 4 + r];

  for (int k = 0; k < 9; k++) {
    const int ky = k / 3, kx = k - ky * 3;
    const float py = (float)(h - 1 + ky) + offb[(2 * k) * HW];
    const float px = (float)(w - 1 + kx) + offb[(2 * k + 1) * HW];
    const float y0f = floorf(py), x0f = floorf(px);
    const float ly = py - y0f, lx = px - x0f;
    const int y0 = (int)y0f, x0 = (int)x0f;
    const int y1 = y0 + 1, x1 = x0 + 1;
    float w00 = (1.f - ly) * (1.f - lx);
    float w01 = (1.f - ly) * lx;
    float w10 = ly * (1.f - lx);
    float w11 = ly * lx;
    if (y0 < 0 || y0 >= HH) { w00 = 0.f; w01 = 0.f; }
    if (y1 < 0 || y1 >= HH) { w10 = 0.f; w11 = 0.f; }
    if (x0 < 0 || x0 >= WW) { w00 = 0.f; w10 = 0.f; }
    if (x1 < 0 || x1 >= WW) { w01 = 0.f; w11 = 0.f; }
    const int cy0 = min(max(y0, 0), HH - 1), cy1 = min(max(y1, 0), HH - 1);
    const int cx0 = min(max(x0, 0), WW - 1), cx1 = min(max(x1, 0), WW - 1);
    const int i00 = cy0 * WW + cx0, i01 = cy0 * WW + cx1;
    const int i10 = cy1 * WW + cx0, i11 = cy1 * WW + cx1;

    bf16x8 bf[2];
#pragma unroll
    for (int cf = 0; cf < 2; cf++) {
#pragma unroll
      for (int j = 0; j < 8; j++) {
        const short* xc = xq + (size_t)(cf * 32 + j) * HW;
        float s = bf2f(xc[i00]) * w00 + bf2f(xc[i01]) * w01 +
                  bf2f(xc[i10]) * w10 + bf2f(xc[i11]) * w11;
        bf[cf][j] = f2bf(s);
      }
    }

    const bf16x8* wp = (const bf16x8*)wtd + (size_t)(k * 2 * 4) * 64 + l;
#pragma unroll
    for (int ot = 0; ot < 4; ot++) {
      acc[ot] = __builtin_amdgcn_mfma_f32_16x16x32_bf16(
          wp[ot * 64], bf[0], acc[ot], 0, 0, 0);
      acc[ot] = __builtin_amdgcn_mfma_f32_16x16x32_bf16(
          wp[(4 + ot) * 64], bf[1], acc[ot], 0, 0, 0);
    }
  }

#pragma unroll
  for (int ot = 0; ot < 4; ot++) {
#pragma unroll
    for (int r = 0; r < 4; r++) {
      const int o = ot * 16 + quad * 4 + r;  // D: row=(l>>4)*4+r, col=l&15
      const size_t oidx = (size_t)b * (CC * HW) + (size_t)o * HW + hw;
      if (outf) outf[oidx] = acc[ot][r];
      if (outb) outb[oidx] = f2bf(acc[ot][r]);
    }
  }
}

extern "C" void kernel_launch(void* const* d_in, const int* in_sizes, int n_in,
                              void* d_out, int out_size, void* d_ws, size_t ws_size,
                              hipStream_t stream) {
  const float* ref    = (const float*)d_in[0];
  const float* nbr    = (const float*)d_in[1];
  const float* w_off1 = (const float*)d_in[2];
  const float* b_off1 = (const float*)d_in[3];
  const float* w_d1   = (const float*)d_in[4];
  const float* b_d1   = (const float*)d_in[5];
  const float* w_off2 = (const float*)d_in[6];
  const float* b_off2 = (const float*)d_in[7];
  const float* w_d2   = (const float*)d_in[8];
  const float* b_d2   = (const float*)d_in[9];
  const float* w_off3 = (const float*)d_in[10];
  const float* b_off3 = (const float*)d_in[11];
  const float* w_d3   = (const float*)d_in[12];
  const float* b_d3   = (const float*)d_in[13];

  float* out = (float*)d_out;
  char* ws = (char*)d_ws;
  // byte layout
  float* off_buf = (float*)(ws);                       // 4,718,592 B
  short* ref_bf  = (short*)(ws + 4718592);             // 8,388,608 B
  short* nbr_bf  = (short*)(ws + 13107200);            // 8,388,608 B
  short* d1_bf   = (short*)(ws + 21495808);            // 8,388,608 B
  short* d2_bf   = (short*)(ws + 29884416);            // 8,388,608 B
  short* wtd1    = (short*)(ws + 38273024);            // 73,728 B each
  short* wtd2    = (short*)(ws + 38346752);
  short* wtd3    = (short*)(ws + 38420480);
  float* to1     = (float*)(ws + 38494208);            // 92,160 B each
  float* to2     = (float*)(ws + 38586368);
  float* to3     = (float*)(ws + 38678528);

  cast_bf16_kernel<<<2048, 256, 0, stream>>>(ref, nbr, ref_bf, nbr_bf,
                                             BB * CC * HW);
  prep_weights<<<144, 256, 0, stream>>>(w_d1, w_off1, wtd1, to1);
  prep_weights<<<144, 256, 0, stream>>>(w_d2, w_off2, wtd2, to2);
  prep_weights<<<144, 256, 0, stream>>>(w_d3, w_off3, wtd3, to3);

  const int nblk_oc = BB * HW / 128;  // 512
  const int nblk_df = BB * HW / 64;   // 1024

  off_conv_kernel<<<nblk_oc, 512, 0, stream>>>(ref_bf, nbr_bf, to1, b_off1, off_buf);
  deform_mfma_kernel<<<nblk_df, 256, 0, stream>>>(nbr_bf, off_buf, wtd1, b_d1, nullptr, d1_bf);
  off_conv_kernel<<<nblk_oc, 512, 0, stream>>>(ref_bf, d1_bf, to2, b_off2, off_buf);
  deform_mfma_kernel<<<nblk_df, 256, 0, stream>>>(d1_bf, off_buf, wtd2, b_d2, nullptr, d2_bf);
  off_conv_kernel<<<nblk_oc, 512, 0, stream>>>(ref_bf, d2_bf, to3, b_off3, off_buf);
  deform_mfma_kernel<<<nblk_df, 256, 0, stream>>>(d2_bf, off_buf, wtd3, b_d3, out, nullptr);
}

// Round 4
// 224.707 us; speedup vs baseline: 2.4126x; 2.4126x over previous
//
#include <hip/hip_runtime.h>
#include <hip/hip_bf16.h>

#define BB 4
#define CC 64
#define HH 128
#define WW 128
#define HW (HH * WW)
#define OCP 20  // offset channels, padded (18 used)

typedef short bf16x8 __attribute__((ext_vector_type(8)));
typedef float f32x4 __attribute__((ext_vector_type(4)));
typedef float f32x2 __attribute__((ext_vector_type(2)));

static __device__ __forceinline__ short f2bf(float f) {
  __hip_bfloat16 h = __float2bfloat16(f);
  return __builtin_bit_cast(short, h);
}
static __device__ __forceinline__ float bf2f(short s) {
  unsigned int u = ((unsigned int)(unsigned short)s) << 16;
  return __builtin_bit_cast(float, u);
}

// NCHW f32 -> NHWC bf16 for two tensors. Block = 64 px x 64 c tile.
__global__ __launch_bounds__(256) void cast_nhwc_kernel(
    const float* __restrict__ a, const float* __restrict__ b,
    short* __restrict__ oa, short* __restrict__ ob) {
  __shared__ float tile[64][68];
  const int bid = blockIdx.x;        // 1024 blocks
  const int bb = bid >> 8;           // batch
  const int hw0 = (bid & 255) * 64;  // 64-px stripe
  const int t = threadIdx.x;
  for (int s = 0; s < 2; s++) {
    const float* src = s ? b : a;
    short* dst = s ? ob : oa;
    if (s) __syncthreads();
    {
      const int lp = t & 15;  // 16 lanes x float4 = 64 px
      for (int c = (t >> 4); c < 64; c += 16) {
        float4 v = *(const float4*)&src[((size_t)(bb * 64 + c)) * HW + hw0 + lp * 4];
        *(float4*)&tile[c][lp * 4] = v;
      }
    }
    __syncthreads();
    {
      const int px = t >> 2;
      const int seg = t & 3;
      bf16x8 s0, s1;
#pragma unroll
      for (int i = 0; i < 8; i++) s0[i] = f2bf(tile[seg * 16 + i][px]);
#pragma unroll
      for (int i = 0; i < 8; i++) s1[i] = f2bf(tile[seg * 16 + 8 + i][px]);
      short* dp = dst + ((size_t)(bid * 64 + px)) * 64 + seg * 16;
      *(bf16x8*)dp = s0;
      *(bf16x8*)(dp + 8) = s1;
    }
  }
}

// Weight prep for one stage.
// deform wd (64,64,3,3) -> A-frags [f = k*8+cf*4+ot][lane][8]:
//   o = ot*16+(l&15), c = cf*32+(l>>4)*8+j
// offset wo (18,128,3,3) -> A-frags [f = (k*4+cs)*2+ot][lane][8]:
//   o = ot*16+(l&15) (zero if o>=18), c = cs*32+(l>>4)*8+j
__global__ __launch_bounds__(256) void prep_weights(
    const float* __restrict__ wd, const float* __restrict__ wo,
    short* __restrict__ wtd, short* __restrict__ wtoff) {
  const int i = blockIdx.x * 256 + threadIdx.x;  // 0..36863
  const int j = i & 7, l = (i >> 3) & 63, f = i >> 9;
  {
    int ot = f & 3, cf = (f >> 2) & 1, k = f >> 3;
    int o = ot * 16 + (l & 15), c = cf * 32 + (l >> 4) * 8 + j;
    wtd[i] = f2bf(wd[(o * 64 + c) * 9 + k]);
  }
  {
    int ot = f & 1, ks = f >> 1;
    int cs = ks & 3, k = ks >> 2;
    int o = ot * 16 + (l & 15), c = cs * 32 + (l >> 4) * 8 + j;
    wtoff[i] = (o < 18) ? f2bf(wo[(o * 128 + c) * 9 + k]) : (short)0;
  }
}

// MFMA offset conv: conv3x3(concat(ref,x2)) + bias -> NHWC f32 [pix][20].
// Wave = 16 px x 32 rows (18 used). B-frag = one bf16x8 NHWC load per (k,cs).
__global__ __launch_bounds__(256, 4) void off_conv_kernel(
    const short* __restrict__ ref, const short* __restrict__ x2,
    const short* __restrict__ wtoff, const float* __restrict__ bias,
    float* __restrict__ out) {
  int bid = blockIdx.x;
  bid = (bid & 7) * (gridDim.x >> 3) + (bid >> 3);
  const int tid = threadIdx.x;
  const int l = tid & 63, wv = tid >> 6;
  const int col = l & 15, quad = l >> 4;
  const int pix = bid * 64 + wv * 16 + col;
  const int b = pix >> 14, hw = pix & (HW - 1);
  const int h = hw >> 7, w = hw & (WW - 1);

  f32x4 acc[2];
#pragma unroll
  for (int ot = 0; ot < 2; ot++)
#pragma unroll
    for (int r = 0; r < 4; r++) acc[ot][r] = 0.f;

  const int c0 = quad * 8;
  const bf16x8* wp = (const bf16x8*)wtoff + l;

  for (int k = 0; k < 9; k++) {
    const int ky = k / 3, kx = k - ky * 3;
    const int hh = h + ky - 1, ww2 = w + kx - 1;
    const bool valid = (hh >= 0) & (hh < HH) & (ww2 >= 0) & (ww2 < WW);
    const int ch = min(max(hh, 0), HH - 1), cw = min(max(ww2, 0), WW - 1);
    const size_t pbase = ((size_t)b * HW + ch * WW + cw) * 64;
#pragma unroll
    for (int cs = 0; cs < 4; cs++) {
      const int c = cs * 32 + c0;
      const short* src = (cs < 2) ? (ref + pbase + c) : (x2 + pbase + c - 64);
      bf16x8 v = *(const bf16x8*)src;
      if (!valid) v = (bf16x8)(short)0;
      const int f = (k * 4 + cs) * 2;
      acc[0] = __builtin_amdgcn_mfma_f32_16x16x32_bf16(wp[f * 64], v, acc[0], 0, 0, 0);
      acc[1] = __builtin_amdgcn_mfma_f32_16x16x32_bf16(wp[(f + 1) * 64], v, acc[1], 0, 0, 0);
    }
  }

  float* po = out + (size_t)pix * OCP;
#pragma unroll
  for (int r = 0; r < 4; r++) po[quad * 4 + r] = acc[0][r] + bias[quad * 4 + r];
  if (quad == 0) {
    po[16] = acc[1][0] + bias[16];
    po[17] = acc[1][1] + bias[17];
  }
}

// MFMA deformable conv, NHWC. Wave = 16 px x 64 outputs. Per tap per cf:
// 4 corner loads (bf16x8, contiguous channels) -> f32 blend -> B-frag.
__global__ __launch_bounds__(256, 4) void deform_mfma_kernel(
    const short* __restrict__ x, const float* __restrict__ off,
    const short* __restrict__ wtd, const float* __restrict__ bias,
    float* __restrict__ outf, short* __restrict__ outb) {
  int bid = blockIdx.x;
  bid = (bid & 7) * (gridDim.x >> 3) + (bid >> 3);
  const int tid = threadIdx.x;
  const int l = tid & 63, wv = tid >> 6;
  const int col = l & 15, quad = l >> 4;
  const int pix = bid * 64 + wv * 16 + col;
  const int b = pix >> 14, hw = pix & (HW - 1);
  const int h = hw >> 7, w = hw & (WW - 1);

  const short* xb = x + (size_t)b * (HW * 64);
  const float* offp = off + (size_t)pix * OCP;

  f32x4 acc[4];
#pragma unroll
  for (int ot = 0; ot < 4; ot++)
#pragma unroll
    for (int r = 0; r < 4; r++) acc[ot][r] = bias[ot * 16 + quad * 4 + r];

  const int c0 = quad * 8;
  const bf16x8* wp = (const bf16x8*)wtd + l;

  for (int k = 0; k < 9; k++) {
    const int ky = k / 3, kx = k - ky * 3;
    const f32x2 od = *(const f32x2*)(offp + 2 * k);
    const float py = (float)(h - 1 + ky) + od[0];
    const float px = (float)(w - 1 + kx) + od[1];
    const float y0f = floorf(py), x0f = floorf(px);
    const float ly = py - y0f, lx = px - x0f;
    const int y0 = (int)y0f, x0 = (int)x0f;
    const int y1 = y0 + 1, x1 = x0 + 1;
    float w00 = (1.f - ly) * (1.f - lx);
    float w01 = (1.f - ly) * lx;
    float w10 = ly * (1.f - lx);
    float w11 = ly * lx;
    if (y0 < 0 || y0 >= HH) { w00 = 0.f; w01 = 0.f; }
    if (y1 < 0 || y1 >= HH) { w10 = 0.f; w11 = 0.f; }
    if (x0 < 0 || x0 >= WW) { w00 = 0.f; w10 = 0.f; }
    if (x1 < 0 || x1 >= WW) { w01 = 0.f; w11 = 0.f; }
    const int cy0 = min(max(y0, 0), HH - 1), cy1 = min(max(y1, 0), HH - 1);
    const int cx0 = min(max(x0, 0), WW - 1), cx1 = min(max(x1, 0), WW - 1);
    const size_t p00 = (size_t)(cy0 * WW + cx0) * 64 + c0;
    const size_t p01 = (size_t)(cy0 * WW + cx1) * 64 + c0;
    const size_t p10 = (size_t)(cy1 * WW + cx0) * 64 + c0;
    const size_t p11 = (size_t)(cy1 * WW + cx1) * 64 + c0;

    bf16x8 v00a = *(const bf16x8*)(xb + p00);
    bf16x8 v00b = *(const bf16x8*)(xb + p00 + 32);
    bf16x8 v01a = *(const bf16x8*)(xb + p01);
    bf16x8 v01b = *(const bf16x8*)(xb + p01 + 32);
    bf16x8 v10a = *(const bf16x8*)(xb + p10);
    bf16x8 v10b = *(const bf16x8*)(xb + p10 + 32);
    bf16x8 v11a = *(const bf16x8*)(xb + p11);
    bf16x8 v11b = *(const bf16x8*)(xb + p11 + 32);

    bf16x8 s0, s1;
#pragma unroll
    for (int j = 0; j < 8; j++) {
      float sa = bf2f(v00a[j]) * w00 + bf2f(v01a[j]) * w01 +
                 bf2f(v10a[j]) * w10 + bf2f(v11a[j]) * w11;
      s0[j] = f2bf(sa);
      float sb = bf2f(v00b[j]) * w00 + bf2f(v01b[j]) * w01 +
                 bf2f(v10b[j]) * w10 + bf2f(v11b[j]) * w11;
      s1[j] = f2bf(sb);
    }

#pragma unroll
    for (int ot = 0; ot < 4; ot++) {
      acc[ot] = __builtin_amdgcn_mfma_f32_16x16x32_bf16(
          wp[(k * 8 + ot) * 64], s0, acc[ot], 0, 0, 0);
      acc[ot] = __builtin_amdgcn_mfma_f32_16x16x32_bf16(
          wp[(k * 8 + 4 + ot) * 64], s1, acc[ot], 0, 0, 0);
    }
  }

  if (outb) {
#pragma unroll
    for (int ot = 0; ot < 4; ot++) {
      short4 sv;
      sv.x = f2bf(acc[ot][0]); sv.y = f2bf(acc[ot][1]);
      sv.z = f2bf(acc[ot][2]); sv.w = f2bf(acc[ot][3]);
      *(short4*)(outb + (size_t)pix * 64 + ot * 16 + quad * 4) = sv;
    }
  }
  if (outf) {
#pragma unroll
    for (int ot = 0; ot < 4; ot++)
#pragma unroll
      for (int r = 0; r < 4; r++) {
        const int o = ot * 16 + quad * 4 + r;
        outf[(size_t)b * (CC * HW) + (size_t)o * HW + hw] = acc[ot][r];
      }
  }
}

extern "C" void kernel_launch(void* const* d_in, const int* in_sizes, int n_in,
                              void* d_out, int out_size, void* d_ws, size_t ws_size,
                              hipStream_t stream) {
  const float* ref    = (const float*)d_in[0];
  const float* nbr    = (const float*)d_in[1];
  const float* w_off1 = (const float*)d_in[2];
  const float* b_off1 = (const float*)d_in[3];
  const float* w_d1   = (const float*)d_in[4];
  const float* b_d1   = (const float*)d_in[5];
  const float* w_off2 = (const float*)d_in[6];
  const float* b_off2 = (const float*)d_in[7];
  const float* w_d2   = (const float*)d_in[8];
  const float* b_d2   = (const float*)d_in[9];
  const float* w_off3 = (const float*)d_in[10];
  const float* b_off3 = (const float*)d_in[11];
  const float* w_d3   = (const float*)d_in[12];
  const float* b_d3   = (const float*)d_in[13];

  float* out = (float*)d_out;
  char* ws = (char*)d_ws;
  float* off_buf = (float*)(ws);               // 4*16384*20*4 = 5,242,880 B
  short* ref_bf  = (short*)(ws + 5242880);     // 8,388,608 B each
  short* nbr_bf  = (short*)(ws + 13631488);
  short* d1_bf   = (short*)(ws + 22020096);
  short* d2_bf   = (short*)(ws + 30408704);
  short* wtd1    = (short*)(ws + 38797312);    // 73,728 B each
  short* wtd2    = (short*)(ws + 38871040);
  short* wtd3    = (short*)(ws + 38944768);
  short* wtoff1  = (short*)(ws + 39018496);
  short* wtoff2  = (short*)(ws + 39092224);
  short* wtoff3  = (short*)(ws + 39165952);

  cast_nhwc_kernel<<<1024, 256, 0, stream>>>(ref, nbr, ref_bf, nbr_bf);
  prep_weights<<<144, 256, 0, stream>>>(w_d1, w_off1, wtd1, wtoff1);
  prep_weights<<<144, 256, 0, stream>>>(w_d2, w_off2, wtd2, wtoff2);
  prep_weights<<<144, 256, 0, stream>>>(w_d3, w_off3, wtd3, wtoff3);

  const int nblk = BB * HW / 64;  // 1024

  off_conv_kernel<<<nblk, 256, 0, stream>>>(ref_bf, nbr_bf, wtoff1, b_off1, off_buf);
  deform_mfma_kernel<<<nblk, 256, 0, stream>>>(nbr_bf, off_buf, wtd1, b_d1, nullptr, d1_bf);
  off_conv_kernel<<<nblk, 256, 0, stream>>>(ref_bf, d1_bf, wtoff2, b_off2, off_buf);
  deform_mfma_kernel<<<nblk, 256, 0, stream>>>(d1_bf, off_buf, wtd2, b_d2, nullptr, d2_bf);
  off_conv_kernel<<<nblk, 256, 0, stream>>>(ref_bf, d2_bf, wtoff3, b_off3, off_buf);
  deform_mfma_kernel<<<nblk, 256, 0, stream>>>(d2_bf, off_buf, wtd3, b_d3, out, nullptr);
}

// Round 5
// 218.955 us; speedup vs baseline: 2.4759x; 1.0263x over previous
//
#include <hip/hip_runtime.h>
#include <hip/hip_bf16.h>

#define BB 4
#define CC 64
#define HH 128
#define WW 128
#define HW (HH * WW)
#define OCP 20  // offset channels, padded (18 used)

typedef short bf16x8 __attribute__((ext_vector_type(8)));
typedef float f32x4 __attribute__((ext_vector_type(4)));
typedef float f32x2 __attribute__((ext_vector_type(2)));

static __device__ __forceinline__ short f2bf(float f) {
  __hip_bfloat16 h = __float2bfloat16(f);
  return __builtin_bit_cast(short, h);
}
static __device__ __forceinline__ float bf2f(short s) {
  unsigned int u = ((unsigned int)(unsigned short)s) << 16;
  return __builtin_bit_cast(float, u);
}

// NCHW f32 -> NHWC bf16 for two tensors. Block = 64 px x 64 c tile.
__global__ __launch_bounds__(256) void cast_nhwc_kernel(
    const float* __restrict__ a, const float* __restrict__ b,
    short* __restrict__ oa, short* __restrict__ ob) {
  __shared__ float tile[64][68];
  const int bid = blockIdx.x;        // 1024 blocks
  const int bb = bid >> 8;           // batch
  const int hw0 = (bid & 255) * 64;  // 64-px stripe
  const int t = threadIdx.x;
  for (int s = 0; s < 2; s++) {
    const float* src = s ? b : a;
    short* dst = s ? ob : oa;
    if (s) __syncthreads();
    {
      const int lp = t & 15;  // 16 lanes x float4 = 64 px
      for (int c = (t >> 4); c < 64; c += 16) {
        float4 v = *(const float4*)&src[((size_t)(bb * 64 + c)) * HW + hw0 + lp * 4];
        *(float4*)&tile[c][lp * 4] = v;
      }
    }
    __syncthreads();
    {
      const int px = t >> 2;
      const int seg = t & 3;
      bf16x8 s0, s1;
#pragma unroll
      for (int i = 0; i < 8; i++) s0[i] = f2bf(tile[seg * 16 + i][px]);
#pragma unroll
      for (int i = 0; i < 8; i++) s1[i] = f2bf(tile[seg * 16 + 8 + i][px]);
      short* dp = dst + ((size_t)(bid * 64 + px)) * 64 + seg * 16;
      *(bf16x8*)dp = s0;
      *(bf16x8*)(dp + 8) = s1;
    }
  }
}

// Weight prep, all 3 stages in one launch (stage = blockIdx.x/144).
// deform wd (64,64,3,3) -> A-frags [f = k*8+cf*4+ot][lane][8]:
//   o = ot*16+(l&15), c = cf*32+(l>>4)*8+j
// offset wo (18,128,3,3) -> A-frags [f = (k*4+cs)*2+ot][lane][8]:
//   o = ot*16+(l&15) (zero if o>=18), c = cs*32+(l>>4)*8+j
__global__ __launch_bounds__(256) void prep_weights_all(
    const float* __restrict__ wd1, const float* __restrict__ wo1,
    short* __restrict__ wtd1, short* __restrict__ wtoff1,
    const float* __restrict__ wd2, const float* __restrict__ wo2,
    short* __restrict__ wtd2, short* __restrict__ wtoff2,
    const float* __restrict__ wd3, const float* __restrict__ wo3,
    short* __restrict__ wtd3, short* __restrict__ wtoff3) {
  const int s = blockIdx.x / 144;
  const float* wd = (s == 0) ? wd1 : (s == 1) ? wd2 : wd3;
  const float* wo = (s == 0) ? wo1 : (s == 1) ? wo2 : wo3;
  short* wtd = (s == 0) ? wtd1 : (s == 1) ? wtd2 : wtd3;
  short* wtoff = (s == 0) ? wtoff1 : (s == 1) ? wtoff2 : wtoff3;
  const int i = (blockIdx.x % 144) * 256 + threadIdx.x;  // 0..36863
  const int j = i & 7, l = (i >> 3) & 63, f = i >> 9;
  {
    int ot = f & 3, cf = (f >> 2) & 1, k = f >> 3;
    int o = ot * 16 + (l & 15), c = cf * 32 + (l >> 4) * 8 + j;
    wtd[i] = f2bf(wd[(o * 64 + c) * 9 + k]);
  }
  {
    int ot = f & 1, ks = f >> 1;
    int cs = ks & 3, k = ks >> 2;
    int o = ot * 16 + (l & 15), c = cs * 32 + (l >> 4) * 8 + j;
    wtoff[i] = (o < 18) ? f2bf(wo[(o * 128 + c) * 9 + k]) : (short)0;
  }
}

// MFMA offset conv: conv3x3(concat(ref,x2)) + bias -> NHWC f32 [pix][20].
// Wave = 16 px x 32 rows (18 used). Fully unrolled: 36 independent B-loads.
__global__ __launch_bounds__(256, 4) void off_conv_kernel(
    const short* __restrict__ ref, const short* __restrict__ x2,
    const short* __restrict__ wtoff, const float* __restrict__ bias,
    float* __restrict__ out) {
  int bid = blockIdx.x;
  bid = (bid & 7) * (gridDim.x >> 3) + (bid >> 3);
  const int tid = threadIdx.x;
  const int l = tid & 63, wv = tid >> 6;
  const int col = l & 15, quad = l >> 4;
  const int pix = bid * 64 + wv * 16 + col;
  const int b = pix >> 14, hw = pix & (HW - 1);
  const int h = hw >> 7, w = hw & (WW - 1);

  f32x4 acc[2];
#pragma unroll
  for (int ot = 0; ot < 2; ot++)
#pragma unroll
    for (int r = 0; r < 4; r++) acc[ot][r] = 0.f;

  const int c0 = quad * 8;
  const bf16x8* wp = (const bf16x8*)wtoff + l;

#pragma unroll
  for (int k = 0; k < 9; k++) {
    const int ky = k / 3, kx = k - ky * 3;
    const int hh = h + ky - 1, ww2 = w + kx - 1;
    const bool valid = (hh >= 0) & (hh < HH) & (ww2 >= 0) & (ww2 < WW);
    const int ch = min(max(hh, 0), HH - 1), cw = min(max(ww2, 0), WW - 1);
    const size_t pbase = ((size_t)b * HW + ch * WW + cw) * 64;
    bf16x8 v[4];
    v[0] = *(const bf16x8*)(ref + pbase + c0);
    v[1] = *(const bf16x8*)(ref + pbase + 32 + c0);
    v[2] = *(const bf16x8*)(x2 + pbase + c0);
    v[3] = *(const bf16x8*)(x2 + pbase + 32 + c0);
#pragma unroll
    for (int cs = 0; cs < 4; cs++) {
      bf16x8 vv = valid ? v[cs] : (bf16x8)(short)0;
      const int f = (k * 4 + cs) * 2;
      acc[0] = __builtin_amdgcn_mfma_f32_16x16x32_bf16(wp[f * 64], vv, acc[0], 0, 0, 0);
      acc[1] = __builtin_amdgcn_mfma_f32_16x16x32_bf16(wp[(f + 1) * 64], vv, acc[1], 0, 0, 0);
    }
  }

  float* po = out + (size_t)pix * OCP;
#pragma unroll
  for (int r = 0; r < 4; r++) po[quad * 4 + r] = acc[0][r] + bias[quad * 4 + r];
  if (quad == 0) {
    po[16] = acc[1][0] + bias[16];
    po[17] = acc[1][1] + bias[17];
  }
}

// MFMA deformable conv, NHWC. Wave = 16 px x 64 outputs. All 18 offsets
// loaded upfront; 9-tap loop fully unrolled so the 72 corner gathers are
// independent straight-line loads the scheduler can software-pipeline.
__global__ __launch_bounds__(256, 4) void deform_mfma_kernel(
    const short* __restrict__ x, const float* __restrict__ off,
    const short* __restrict__ wtd, const float* __restrict__ bias,
    float* __restrict__ outf, short* __restrict__ outb) {
  int bid = blockIdx.x;
  bid = (bid & 7) * (gridDim.x >> 3) + (bid >> 3);
  const int tid = threadIdx.x;
  const int l = tid & 63, wv = tid >> 6;
  const int col = l & 15, quad = l >> 4;
  const int pix = bid * 64 + wv * 16 + col;
  const int b = pix >> 14, hw = pix & (HW - 1);
  const int h = hw >> 7, w = hw & (WW - 1);

  const short* xb = x + (size_t)b * (HW * 64);
  const float* offp = off + (size_t)pix * OCP;

  // all 18 offset values in 5 vector loads
  f32x4 ov0 = *(const f32x4*)(offp);
  f32x4 ov1 = *(const f32x4*)(offp + 4);
  f32x4 ov2 = *(const f32x4*)(offp + 8);
  f32x4 ov3 = *(const f32x4*)(offp + 12);
  f32x2 ov4 = *(const f32x2*)(offp + 16);
  float offv[18];
#pragma unroll
  for (int i = 0; i < 4; i++) offv[i] = ov0[i];
#pragma unroll
  for (int i = 0; i < 4; i++) offv[4 + i] = ov1[i];
#pragma unroll
  for (int i = 0; i < 4; i++) offv[8 + i] = ov2[i];
#pragma unroll
  for (int i = 0; i < 4; i++) offv[12 + i] = ov3[i];
  offv[16] = ov4[0];
  offv[17] = ov4[1];

  f32x4 acc[4];
#pragma unroll
  for (int ot = 0; ot < 4; ot++)
#pragma unroll
    for (int r = 0; r < 4; r++) acc[ot][r] = bias[ot * 16 + quad * 4 + r];

  const int c0 = quad * 8;
  const bf16x8* wp = (const bf16x8*)wtd + l;

#pragma unroll
  for (int k = 0; k < 9; k++) {
    const int ky = k / 3, kx = k - ky * 3;
    const float py = (float)(h - 1 + ky) + offv[2 * k];
    const float px = (float)(w - 1 + kx) + offv[2 * k + 1];
    const float y0f = floorf(py), x0f = floorf(px);
    const float ly = py - y0f, lx = px - x0f;
    const int y0 = (int)y0f, x0 = (int)x0f;
    const int y1 = y0 + 1, x1 = x0 + 1;
    float w00 = (1.f - ly) * (1.f - lx);
    float w01 = (1.f - ly) * lx;
    float w10 = ly * (1.f - lx);
    float w11 = ly * lx;
    if (y0 < 0 || y0 >= HH) { w00 = 0.f; w01 = 0.f; }
    if (y1 < 0 || y1 >= HH) { w10 = 0.f; w11 = 0.f; }
    if (x0 < 0 || x0 >= WW) { w00 = 0.f; w10 = 0.f; }
    if (x1 < 0 || x1 >= WW) { w01 = 0.f; w11 = 0.f; }
    const int cy0 = min(max(y0, 0), HH - 1), cy1 = min(max(y1, 0), HH - 1);
    const int cx0 = min(max(x0, 0), WW - 1), cx1 = min(max(x1, 0), WW - 1);
    const int p00 = ((cy0 * WW + cx0) << 6) + c0;
    const int p01 = ((cy0 * WW + cx1) << 6) + c0;
    const int p10 = ((cy1 * WW + cx0) << 6) + c0;
    const int p11 = ((cy1 * WW + cx1) << 6) + c0;

    bf16x8 v00a = *(const bf16x8*)(xb + p00);
    bf16x8 v00b = *(const bf16x8*)(xb + p00 + 32);
    bf16x8 v01a = *(const bf16x8*)(xb + p01);
    bf16x8 v01b = *(const bf16x8*)(xb + p01 + 32);
    bf16x8 v10a = *(const bf16x8*)(xb + p10);
    bf16x8 v10b = *(const bf16x8*)(xb + p10 + 32);
    bf16x8 v11a = *(const bf16x8*)(xb + p11);
    bf16x8 v11b = *(const bf16x8*)(xb + p11 + 32);

    bf16x8 s0, s1;
#pragma unroll
    for (int j = 0; j < 8; j++) {
      float sa = bf2f(v00a[j]) * w00 + bf2f(v01a[j]) * w01 +
                 bf2f(v10a[j]) * w10 + bf2f(v11a[j]) * w11;
      s0[j] = f2bf(sa);
      float sb = bf2f(v00b[j]) * w00 + bf2f(v01b[j]) * w01 +
                 bf2f(v10b[j]) * w10 + bf2f(v11b[j]) * w11;
      s1[j] = f2bf(sb);
    }

#pragma unroll
    for (int ot = 0; ot < 4; ot++) {
      acc[ot] = __builtin_amdgcn_mfma_f32_16x16x32_bf16(
          wp[(k * 8 + ot) * 64], s0, acc[ot], 0, 0, 0);
      acc[ot] = __builtin_amdgcn_mfma_f32_16x16x32_bf16(
          wp[(k * 8 + 4 + ot) * 64], s1, acc[ot], 0, 0, 0);
    }
  }

  if (outb) {
#pragma unroll
    for (int ot = 0; ot < 4; ot++) {
      short4 sv;
      sv.x = f2bf(acc[ot][0]); sv.y = f2bf(acc[ot][1]);
      sv.z = f2bf(acc[ot][2]); sv.w = f2bf(acc[ot][3]);
      *(short4*)(outb + (size_t)pix * 64 + ot * 16 + quad * 4) = sv;
    }
  }
  if (outf) {
#pragma unroll
    for (int ot = 0; ot < 4; ot++)
#pragma unroll
      for (int r = 0; r < 4; r++) {
        const int o = ot * 16 + quad * 4 + r;
        outf[(size_t)b * (CC * HW) + (size_t)o * HW + hw] = acc[ot][r];
      }
  }
}

extern "C" void kernel_launch(void* const* d_in, const int* in_sizes, int n_in,
                              void* d_out, int out_size, void* d_ws, size_t ws_size,
                              hipStream_t stream) {
  const float* ref    = (const float*)d_in[0];
  const float* nbr    = (const float*)d_in[1];
  const float* w_off1 = (const float*)d_in[2];
  const float* b_off1 = (const float*)d_in[3];
  const float* w_d1   = (const float*)d_in[4];
  const float* b_d1   = (const float*)d_in[5];
  const float* w_off2 = (const float*)d_in[6];
  const float* b_off2 = (const float*)d_in[7];
  const float* w_d2   = (const float*)d_in[8];
  const float* b_d2   = (const float*)d_in[9];
  const float* w_off3 = (const float*)d_in[10];
  const float* b_off3 = (const float*)d_in[11];
  const float* w_d3   = (const float*)d_in[12];
  const float* b_d3   = (const float*)d_in[13];

  float* out = (float*)d_out;
  char* ws = (char*)d_ws;
  float* off_buf = (float*)(ws);               // 4*16384*20*4 = 5,242,880 B
  short* ref_bf  = (short*)(ws + 5242880);     // 8,388,608 B each
  short* nbr_bf  = (short*)(ws + 13631488);
  short* d1_bf   = (short*)(ws + 22020096);
  short* d2_bf   = (short*)(ws + 30408704);
  short* wtd1    = (short*)(ws + 38797312);    // 73,728 B each
  short* wtd2    = (short*)(ws + 38871040);
  short* wtd3    = (short*)(ws + 38944768);
  short* wtoff1  = (short*)(ws + 39018496);
  short* wtoff2  = (short*)(ws + 39092224);
  short* wtoff3  = (short*)(ws + 39165952);

  cast_nhwc_kernel<<<1024, 256, 0, stream>>>(ref, nbr, ref_bf, nbr_bf);
  prep_weights_all<<<432, 256, 0, stream>>>(
      w_d1, w_off1, wtd1, wtoff1,
      w_d2, w_off2, wtd2, wtoff2,
      w_d3, w_off3, wtd3, wtoff3);

  const int nblk = BB * HW / 64;  // 1024

  off_conv_kernel<<<nblk, 256, 0, stream>>>(ref_bf, nbr_bf, wtoff1, b_off1, off_buf);
  deform_mfma_kernel<<<nblk, 256, 0, stream>>>(nbr_bf, off_buf, wtd1, b_d1, nullptr, d1_bf);
  off_conv_kernel<<<nblk, 256, 0, stream>>>(ref_bf, d1_bf, wtoff2, b_off2, off_buf);
  deform_mfma_kernel<<<nblk, 256, 0, stream>>>(d1_bf, off_buf, wtd2, b_d2, nullptr, d2_bf);
  off_conv_kernel<<<nblk, 256, 0, stream>>>(ref_bf, d2_bf, wtoff3, b_off3, off_buf);
  deform_mfma_kernel<<<nblk, 256, 0, stream>>>(d2_bf, off_buf, wtd3, b_d3, out, nullptr);
}